// Round 5
// baseline (341.463 us; speedup 1.0000x reference)
//
#include <hip/hip_runtime.h>
#include <hip/hip_bf16.h>
#include <stdint.h>

// NeighbourLoss: mean((||p_n - p_idx||^2 - orig)^2) * 1e5
// N = 1<<20 points, K = 16 neighbours.
//
// R5: quantized 4 MB table (L2-resident, from R4) + non-temporal gathers
// (no L1 allocate -> no wasted 64B fills / MSHR hold) + 2 points per thread
// (32 outstanding gathers/lane, 2048 blocks = 8 blocks/CU = 100% occupancy).

#define NPTS 1048576
#define KNBR 16
#define BLOCK 256
#define PPT 2                      // points per thread
#define HALF (NPTS / PPT)

typedef int   vint4   __attribute__((ext_vector_type(4)));
typedef float vfloat4 __attribute__((ext_vector_type(4)));

__global__ __launch_bounds__(BLOCK) void quantize_points(
    const float* __restrict__ p, uint32_t* __restrict__ tab) {
    int n = blockIdx.x * BLOCK + threadIdx.x;
    float x = __builtin_nontemporal_load(p + 3 * n + 0);
    float y = __builtin_nontemporal_load(p + 3 * n + 1);
    float z = __builtin_nontemporal_load(p + 3 * n + 2);
    int ux = (int)rintf(x * 64.0f) + 512;
    int uy = (int)rintf(y * 64.0f) + 512;
    int uz = (int)rintf(z * 64.0f) + 512;
    ux = min(1023, max(0, ux));
    uy = min(1023, max(0, uy));
    uz = min(1023, max(0, uz));
    tab[n] = (uint32_t)ux | ((uint32_t)uy << 10) | ((uint32_t)uz << 20);
}

__device__ __forceinline__ float point_terms(
    int n, const uint32_t* __restrict__ tab,
    const float* __restrict__ points,
    const int* __restrict__ nbr,
    const float* __restrict__ orig) {

    const float px = __builtin_nontemporal_load(points + 3 * n + 0);
    const float py = __builtin_nontemporal_load(points + 3 * n + 1);
    const float pz = __builtin_nontemporal_load(points + 3 * n + 2);

    const vint4*   nb4 = (const vint4*)(nbr  + (size_t)n * KNBR);
    const vfloat4* od4 = (const vfloat4*)(orig + (size_t)n * KNBR);

    vint4   id0 = __builtin_nontemporal_load(nb4 + 0);
    vint4   id1 = __builtin_nontemporal_load(nb4 + 1);
    vint4   id2 = __builtin_nontemporal_load(nb4 + 2);
    vint4   id3 = __builtin_nontemporal_load(nb4 + 3);
    vfloat4 od0 = __builtin_nontemporal_load(od4 + 0);
    vfloat4 od1 = __builtin_nontemporal_load(od4 + 1);
    vfloat4 od2 = __builtin_nontemporal_load(od4 + 2);
    vfloat4 od3 = __builtin_nontemporal_load(od4 + 3);

    int ids[16] = { id0[0], id0[1], id0[2], id0[3],
                    id1[0], id1[1], id1[2], id1[3],
                    id2[0], id2[1], id2[2], id2[3],
                    id3[0], id3[1], id3[2], id3[3] };
    float ods[16] = { od0[0], od0[1], od0[2], od0[3],
                      od1[0], od1[1], od1[2], od1[3],
                      od2[0], od2[1], od2[2], od2[3],
                      od3[0], od3[1], od3[2], od3[3] };

    // all 16 gathers issued back-to-back, non-temporal (no L1 allocate)
    uint32_t w[16];
#pragma unroll
    for (int j = 0; j < 16; ++j)
        w[j] = __builtin_nontemporal_load(tab + ids[j]);

    float local = 0.0f;
#pragma unroll
    for (int j = 0; j < 16; ++j) {
        float qx = (float)(int)(w[j] & 1023u)         * 0.015625f - 8.0f;
        float qy = (float)(int)((w[j] >> 10) & 1023u) * 0.015625f - 8.0f;
        float qz = (float)(int)((w[j] >> 20) & 1023u) * 0.015625f - 8.0f;
        float dx = px - qx;
        float dy = py - qy;
        float dz = pz - qz;
        float curr = fmaf(dx, dx, fmaf(dy, dy, dz * dz));
        float e = curr - ods[j];
        local = fmaf(e, e, local);
    }
    return local;
}

__global__ __launch_bounds__(BLOCK) void nbr_loss_quant(
    const uint32_t* __restrict__ tab,
    const float* __restrict__ points,
    const int* __restrict__ nbr,
    const float* __restrict__ orig,
    double* __restrict__ accum) {

    int t = blockIdx.x * BLOCK + threadIdx.x;

    // strided split keeps every stream load coalesced across lanes
    float local = point_terms(t,        tab, points, nbr, orig)
                + point_terms(t + HALF, tab, points, nbr, orig);

    // wave-64 shuffle reduction
#pragma unroll
    for (int off = 32; off > 0; off >>= 1)
        local += __shfl_down(local, off, 64);

    __shared__ float wsum[BLOCK / 64];
    int lane = threadIdx.x & 63;
    int wid  = threadIdx.x >> 6;
    if (lane == 0) wsum[wid] = local;
    __syncthreads();

    if (threadIdx.x == 0) {
        float s = 0.0f;
#pragma unroll
        for (int wv = 0; wv < BLOCK / 64; ++wv) s += wsum[wv];
        atomicAdd(accum, (double)s);
    }
}

// Fallback (R1 baseline) if workspace is too small.
__global__ __launch_bounds__(BLOCK) void nbr_loss_partial(
    const float* __restrict__ points,
    const int* __restrict__ nbr,
    const float* __restrict__ orig,
    double* __restrict__ accum) {

    int n = blockIdx.x * BLOCK + threadIdx.x;

    const float px = points[3 * n + 0];
    const float py = points[3 * n + 1];
    const float pz = points[3 * n + 2];

    const int4*   nb4 = (const int4*)(nbr  + (size_t)n * KNBR);
    const float4* od4 = (const float4*)(orig + (size_t)n * KNBR);

    float local = 0.0f;
#pragma unroll
    for (int v = 0; v < 4; ++v) {
        int4   id = nb4[v];
        float4 od = od4[v];
        int   ids[4] = { id.x, id.y, id.z, id.w };
        float ods[4] = { od.x, od.y, od.z, od.w };
#pragma unroll
        for (int j = 0; j < 4; ++j) {
            const float* q = points + (size_t)3 * (size_t)ids[j];
            float dx = px - q[0];
            float dy = py - q[1];
            float dz = pz - q[2];
            float curr = dx * dx + dy * dy + dz * dz;
            float e = curr - ods[j];
            local = fmaf(e, e, local);
        }
    }

#pragma unroll
    for (int off = 32; off > 0; off >>= 1)
        local += __shfl_down(local, off, 64);

    __shared__ float wsum[BLOCK / 64];
    int lane = threadIdx.x & 63;
    int wid  = threadIdx.x >> 6;
    if (lane == 0) wsum[wid] = local;
    __syncthreads();

    if (threadIdx.x == 0) {
        float s = 0.0f;
#pragma unroll
        for (int w = 0; w < BLOCK / 64; ++w) s += wsum[w];
        atomicAdd(accum, (double)s);
    }
}

__global__ void nbr_loss_finalize(const double* __restrict__ accum,
                                  float* __restrict__ out) {
    double mean = accum[0] / (double)((long long)NPTS * KNBR);
    out[0] = (float)(mean * 100000.0);
}

extern "C" void kernel_launch(void* const* d_in, const int* in_sizes, int n_in,
                              void* d_out, int out_size, void* d_ws, size_t ws_size,
                              hipStream_t stream) {
    const float* points = (const float*)d_in[0];
    const int*   nbr    = (const int*)d_in[1];
    const float* orig   = (const float*)d_in[2];
    float* out = (float*)d_out;

    // ws layout: [0,8)   double accumulator
    //            [256, 256 + 4MB) packed 10-bit-per-coord point table
    double* accum = (double*)d_ws;
    uint32_t* tab = (uint32_t*)((char*)d_ws + 256);
    const size_t need = 256 + (size_t)NPTS * sizeof(uint32_t);

    (void)hipMemsetAsync(accum, 0, sizeof(double), stream);

    if (ws_size >= need) {
        quantize_points<<<dim3(NPTS / BLOCK), BLOCK, 0, stream>>>(points, tab);
        nbr_loss_quant<<<dim3(HALF / BLOCK), BLOCK, 0, stream>>>(tab, points, nbr, orig, accum);
    } else {
        nbr_loss_partial<<<dim3(NPTS / BLOCK), BLOCK, 0, stream>>>(points, nbr, orig, accum);
    }
    nbr_loss_finalize<<<1, 1, 0, stream>>>(accum, out);
}

// Round 6
// 247.179 us; speedup vs baseline: 1.3814x; 1.3814x over previous
//
#include <hip/hip_runtime.h>
#include <hip/hip_bf16.h>
#include <stdint.h>

// NeighbourLoss: mean((||p_n - p_idx||^2 - orig)^2) * 1e5
// N = 1<<20 points, K = 16 neighbours.
//
// R6: quantized 4 MB table (L2-resident) with NORMAL cached gathers (R5
// proved nt gathers evict the table from L2: FETCH +170MB, dur +55%).
// nt only on read-once streams. PPT=2: 32 gathers in flight per lane to
// test whether the gather ceiling is per-wave tracking or a shared per-CU
// TCP transaction pool.

#define NPTS 1048576
#define KNBR 16
#define BLOCK 256
#define PPT 2
#define HALF (NPTS / PPT)

typedef int   vint4   __attribute__((ext_vector_type(4)));
typedef float vfloat4 __attribute__((ext_vector_type(4)));

__global__ __launch_bounds__(BLOCK) void quantize_points(
    const float* __restrict__ p, uint32_t* __restrict__ tab) {
    int n = blockIdx.x * BLOCK + threadIdx.x;
    float x = __builtin_nontemporal_load(p + 3 * n + 0);
    float y = __builtin_nontemporal_load(p + 3 * n + 1);
    float z = __builtin_nontemporal_load(p + 3 * n + 2);
    int ux = (int)rintf(x * 64.0f) + 512;
    int uy = (int)rintf(y * 64.0f) + 512;
    int uz = (int)rintf(z * 64.0f) + 512;
    ux = min(1023, max(0, ux));
    uy = min(1023, max(0, uy));
    uz = min(1023, max(0, uz));
    tab[n] = (uint32_t)ux | ((uint32_t)uy << 10) | ((uint32_t)uz << 20);
}

__global__ __launch_bounds__(BLOCK) void nbr_loss_quant(
    const uint32_t* __restrict__ tab,
    const float* __restrict__ points,
    const int* __restrict__ nbr,
    const float* __restrict__ orig,
    double* __restrict__ accum) {

    int t = blockIdx.x * BLOCK + threadIdx.x;
    int n0 = t;
    int n1 = t + HALF;

    // centre points (read-once 12B rows -> nt)
    const float px0 = __builtin_nontemporal_load(points + 3 * n0 + 0);
    const float py0 = __builtin_nontemporal_load(points + 3 * n0 + 1);
    const float pz0 = __builtin_nontemporal_load(points + 3 * n0 + 2);
    const float px1 = __builtin_nontemporal_load(points + 3 * n1 + 0);
    const float py1 = __builtin_nontemporal_load(points + 3 * n1 + 1);
    const float pz1 = __builtin_nontemporal_load(points + 3 * n1 + 2);

    const vint4*   nbA = (const vint4*)(nbr  + (size_t)n0 * KNBR);
    const vint4*   nbB = (const vint4*)(nbr  + (size_t)n1 * KNBR);
    const vfloat4* odA = (const vfloat4*)(orig + (size_t)n0 * KNBR);
    const vfloat4* odB = (const vfloat4*)(orig + (size_t)n1 * KNBR);

    // indices first (need them to issue gathers)
    vint4 a0 = __builtin_nontemporal_load(nbA + 0);
    vint4 a1 = __builtin_nontemporal_load(nbA + 1);
    vint4 a2 = __builtin_nontemporal_load(nbA + 2);
    vint4 a3 = __builtin_nontemporal_load(nbA + 3);
    vint4 b0 = __builtin_nontemporal_load(nbB + 0);
    vint4 b1 = __builtin_nontemporal_load(nbB + 1);
    vint4 b2 = __builtin_nontemporal_load(nbB + 2);
    vint4 b3 = __builtin_nontemporal_load(nbB + 3);

    int idsA[16] = { a0[0],a0[1],a0[2],a0[3], a1[0],a1[1],a1[2],a1[3],
                     a2[0],a2[1],a2[2],a2[3], a3[0],a3[1],a3[2],a3[3] };
    int idsB[16] = { b0[0],b0[1],b0[2],b0[3], b1[0],b1[1],b1[2],b1[3],
                     b2[0],b2[1],b2[2],b2[3], b3[0],b3[1],b3[2],b3[3] };

    // issue ALL 32 table gathers back-to-back (cached: table stays in L2)
    uint32_t wA[16], wB[16];
#pragma unroll
    for (int j = 0; j < 16; ++j) wA[j] = tab[idsA[j]];
#pragma unroll
    for (int j = 0; j < 16; ++j) wB[j] = tab[idsB[j]];

    // distances after gathers are in flight
    vfloat4 oA0 = __builtin_nontemporal_load(odA + 0);
    vfloat4 oA1 = __builtin_nontemporal_load(odA + 1);
    vfloat4 oA2 = __builtin_nontemporal_load(odA + 2);
    vfloat4 oA3 = __builtin_nontemporal_load(odA + 3);
    vfloat4 oB0 = __builtin_nontemporal_load(odB + 0);
    vfloat4 oB1 = __builtin_nontemporal_load(odB + 1);
    vfloat4 oB2 = __builtin_nontemporal_load(odB + 2);
    vfloat4 oB3 = __builtin_nontemporal_load(odB + 3);

    float odsA[16] = { oA0[0],oA0[1],oA0[2],oA0[3], oA1[0],oA1[1],oA1[2],oA1[3],
                       oA2[0],oA2[1],oA2[2],oA2[3], oA3[0],oA3[1],oA3[2],oA3[3] };
    float odsB[16] = { oB0[0],oB0[1],oB0[2],oB0[3], oB1[0],oB1[1],oB1[2],oB1[3],
                       oB2[0],oB2[1],oB2[2],oB2[3], oB3[0],oB3[1],oB3[2],oB3[3] };

    float local = 0.0f;
#pragma unroll
    for (int j = 0; j < 16; ++j) {
        float qx = (float)(int)(wA[j] & 1023u)         * 0.015625f - 8.0f;
        float qy = (float)(int)((wA[j] >> 10) & 1023u) * 0.015625f - 8.0f;
        float qz = (float)(int)((wA[j] >> 20) & 1023u) * 0.015625f - 8.0f;
        float dx = px0 - qx, dy = py0 - qy, dz = pz0 - qz;
        float curr = fmaf(dx, dx, fmaf(dy, dy, dz * dz));
        float e = curr - odsA[j];
        local = fmaf(e, e, local);
    }
#pragma unroll
    for (int j = 0; j < 16; ++j) {
        float qx = (float)(int)(wB[j] & 1023u)         * 0.015625f - 8.0f;
        float qy = (float)(int)((wB[j] >> 10) & 1023u) * 0.015625f - 8.0f;
        float qz = (float)(int)((wB[j] >> 20) & 1023u) * 0.015625f - 8.0f;
        float dx = px1 - qx, dy = py1 - qy, dz = pz1 - qz;
        float curr = fmaf(dx, dx, fmaf(dy, dy, dz * dz));
        float e = curr - odsB[j];
        local = fmaf(e, e, local);
    }

    // wave-64 shuffle reduction
#pragma unroll
    for (int off = 32; off > 0; off >>= 1)
        local += __shfl_down(local, off, 64);

    __shared__ float wsum[BLOCK / 64];
    int lane = threadIdx.x & 63;
    int wid  = threadIdx.x >> 6;
    if (lane == 0) wsum[wid] = local;
    __syncthreads();

    if (threadIdx.x == 0) {
        float s = 0.0f;
#pragma unroll
        for (int wv = 0; wv < BLOCK / 64; ++wv) s += wsum[wv];
        atomicAdd(accum, (double)s);
    }
}

// Fallback (R1 baseline) if workspace is too small.
__global__ __launch_bounds__(BLOCK) void nbr_loss_partial(
    const float* __restrict__ points,
    const int* __restrict__ nbr,
    const float* __restrict__ orig,
    double* __restrict__ accum) {

    int n = blockIdx.x * BLOCK + threadIdx.x;

    const float px = points[3 * n + 0];
    const float py = points[3 * n + 1];
    const float pz = points[3 * n + 2];

    const int4*   nb4 = (const int4*)(nbr  + (size_t)n * KNBR);
    const float4* od4 = (const float4*)(orig + (size_t)n * KNBR);

    float local = 0.0f;
#pragma unroll
    for (int v = 0; v < 4; ++v) {
        int4   id = nb4[v];
        float4 od = od4[v];
        int   ids[4] = { id.x, id.y, id.z, id.w };
        float ods[4] = { od.x, od.y, od.z, od.w };
#pragma unroll
        for (int j = 0; j < 4; ++j) {
            const float* q = points + (size_t)3 * (size_t)ids[j];
            float dx = px - q[0];
            float dy = py - q[1];
            float dz = pz - q[2];
            float curr = dx * dx + dy * dy + dz * dz;
            float e = curr - ods[j];
            local = fmaf(e, e, local);
        }
    }

#pragma unroll
    for (int off = 32; off > 0; off >>= 1)
        local += __shfl_down(local, off, 64);

    __shared__ float wsum[BLOCK / 64];
    int lane = threadIdx.x & 63;
    int wid  = threadIdx.x >> 6;
    if (lane == 0) wsum[wid] = local;
    __syncthreads();

    if (threadIdx.x == 0) {
        float s = 0.0f;
#pragma unroll
        for (int w = 0; w < BLOCK / 64; ++w) s += wsum[w];
        atomicAdd(accum, (double)s);
    }
}

__global__ void nbr_loss_finalize(const double* __restrict__ accum,
                                  float* __restrict__ out) {
    double mean = accum[0] / (double)((long long)NPTS * KNBR);
    out[0] = (float)(mean * 100000.0);
}

extern "C" void kernel_launch(void* const* d_in, const int* in_sizes, int n_in,
                              void* d_out, int out_size, void* d_ws, size_t ws_size,
                              hipStream_t stream) {
    const float* points = (const float*)d_in[0];
    const int*   nbr    = (const int*)d_in[1];
    const float* orig   = (const float*)d_in[2];
    float* out = (float*)d_out;

    // ws layout: [0,8)   double accumulator
    //            [256, 256 + 4MB) packed 10-bit-per-coord point table
    double* accum = (double*)d_ws;
    uint32_t* tab = (uint32_t*)((char*)d_ws + 256);
    const size_t need = 256 + (size_t)NPTS * sizeof(uint32_t);

    (void)hipMemsetAsync(accum, 0, sizeof(double), stream);

    if (ws_size >= need) {
        quantize_points<<<dim3(NPTS / BLOCK), BLOCK, 0, stream>>>(points, tab);
        nbr_loss_quant<<<dim3(HALF / BLOCK), BLOCK, 0, stream>>>(tab, points, nbr, orig, accum);
    } else {
        nbr_loss_partial<<<dim3(NPTS / BLOCK), BLOCK, 0, stream>>>(points, nbr, orig, accum);
    }
    nbr_loss_finalize<<<1, 1, 0, stream>>>(accum, out);
}